// Round 4
// baseline (291.193 us; speedup 1.0000x reference)
//
#include <hip/hip_runtime.h>

#define SDIM 2048
#define DDIM 512
#define NB 8

typedef __bf16 bf16x8 __attribute__((ext_vector_type(8)));
typedef float f32x4 __attribute__((ext_vector_type(4)));

__device__ __forceinline__ ushort f2bf(float f) {
  unsigned u = __float_as_uint(f);
  u = (u + 0x7FFFu + ((u >> 16) & 1u)) >> 16;  // RNE
  return (ushort)u;
}

// ---- prepass: K fp32 -> bf16 ----
__global__ void convert_k(const float* __restrict__ K, ushort* __restrict__ Kb) {
  const long N4 = (long)NB * SDIM * DDIM / 4;
  const long stride = (long)gridDim.x * blockDim.x;
  for (long i = (long)blockIdx.x * blockDim.x + threadIdx.x; i < N4; i += stride) {
    float4 k = ((const float4*)K)[i];
    ushort4 o;
    o.x = f2bf(k.x); o.y = f2bf(k.y); o.z = f2bf(k.z); o.w = f2bf(k.w);
    ((ushort4*)Kb)[i] = o;
  }
}

// ---- prepass: V fp32 [b][s][d] -> bf16 V^T [b][d][s] ----
__global__ void transpose_v(const float* __restrict__ V, ushort* __restrict__ Vt) {
  __shared__ float T[64][65];
  int bid = blockIdx.x;
  int b  = bid >> 8;
  int st = (bid >> 3) & 31;
  int dt = bid & 7;
  int t  = threadIdx.x;
  int r  = t >> 4, c4 = (t & 15) << 2;
  const float* src = V + ((size_t)b * SDIM + st * 64) * DDIM + dt * 64;
  #pragma unroll
  for (int i = 0; i < 4; ++i) {
    float4 v = *(const float4*)(src + (size_t)(r + i * 16) * DDIM + c4);
    T[r + i * 16][c4 + 0] = v.x; T[r + i * 16][c4 + 1] = v.y;
    T[r + i * 16][c4 + 2] = v.z; T[r + i * 16][c4 + 3] = v.w;
  }
  __syncthreads();
  ushort* dst = Vt + ((size_t)b * DDIM + dt * 64) * SDIM + st * 64;
  #pragma unroll
  for (int i = 0; i < 4; ++i) {
    int dr = r + i * 16;
    ushort4 o;
    o.x = f2bf(T[c4 + 0][dr]); o.y = f2bf(T[c4 + 1][dr]);
    o.z = f2bf(T[c4 + 2][dr]); o.w = f2bf(T[c4 + 3][dr]);
    *(ushort4*)(dst + (size_t)dr * SDIM + c4) = o;
  }
}

// ---- flash attention: 8 waves = 2 independent 4-wave groups, in-block K-split.
// Block handles q-tiles (63-p) then (p): exactly 33 k-iters/block, uniform.
// Per group: QBLK=32, KBLK=32, K double-buffered (stage at iter top, wait at
// iter end -> full-iteration slack). V read direct from L2 (no LDS staging).
// Partials merged through LDS scratch (aliases dead K buffers).
#define AS1 __attribute__((address_space(1)))
#define AS3 __attribute__((address_space(3)))

__global__ __launch_bounds__(512, 2) void attn(
    const float* __restrict__ Qf, const ushort* __restrict__ Kb,
    const ushort* __restrict__ Vt, float* __restrict__ out) {
  // layout: K[grp][buf] 4x32KB @0; Psh[grp] @131072 (+2560); m[grp][pp][32]
  // @136192 (+256/grp); pmax[grp][ks][32] @136704 (+256/grp)
  __shared__ __align__(16) char lds[137216];

  const int bi  = blockIdx.x;
  const int b   = bi & 7;                 // batch -> XCD affinity
  const int pr  = bi >> 3;                // 0..31
  const int tid = threadIdx.x;
  const int wv  = tid >> 6;               // 0..7
  const int grp = wv >> 2;                // K-split group
  const int w   = wv & 3;                 // wave-in-group
  const int lane = tid & 63;
  const int g    = (lane >> 4) & 3;
  const int m16  = lane & 15;
  const int qs   = w >> 1;
  const int ks   = w & 1;
  const int dw0  = w << 7;                // PV d-slice (128 cols/wave)

  char*   ldsK = lds + grp * 65536;
  ushort* psh  = (ushort*)(lds + 131072 + grp * 2560);   // 32 rows x 80B
  float*  mrow = (float*)(lds + 136192 + grp * 256);     // [pp][32]
  float*  pmx  = (float*)(lds + 136704 + grp * 256);     // [ks][32]

  const ushort* kbb = Kb + (size_t)b * SDIM * DDIM;
  const ushort* vtb = Vt + (size_t)b * DDIM * SDIM;

  const float qscale = 0.022097086912079608f;   // 1/sqrt(2048)
  union { ushort us[8]; bf16x8 v; } onesu;
  #pragma unroll
  for (int i = 0; i < 8; ++i) onesu.us[i] = 0x3F80;
  const bf16x8 ones = onesu.v;
  const f32x4 zero = {0.f, 0.f, 0.f, 0.f};

  for (int tile = 0; tile < 2; ++tile) {
    const int t  = (tile == 0) ? (63 - pr) : pr;
    const int q0 = t << 5;
    const int H  = (t + 2) >> 1;                 // unified trip count
    const int kcount = (grp == 0) ? H : (t + 1 - H);
    const int kbase  = (grp == 0) ? 0 : H;

    // Q fragments (fp32 -> bf16 in-reg, pre-scaled)
    bf16x8 qf[16];
    {
      const float* qrow = Qf + ((size_t)b * SDIM + q0 + qs * 16 + m16) * DDIM + g * 8;
      #pragma unroll
      for (int ds = 0; ds < 16; ++ds) {
        float4 u = *(const float4*)(qrow + ds * 32);
        float4 x = *(const float4*)(qrow + ds * 32 + 4);
        union { ushort us[8]; bf16x8 v; } pk;
        pk.us[0] = f2bf(u.x * qscale); pk.us[1] = f2bf(u.y * qscale);
        pk.us[2] = f2bf(u.z * qscale); pk.us[3] = f2bf(u.w * qscale);
        pk.us[4] = f2bf(x.x * qscale); pk.us[5] = f2bf(x.y * qscale);
        pk.us[6] = f2bf(x.z * qscale); pk.us[7] = f2bf(x.w * qscale);
        qf[ds] = pk.v;
      }
    }

    if (w == 0 && lane < 32) mrow[lane] = -1e30f;    // pp=0 slot

    f32x4 acc[2][8];
    f32x4 acc1[2];
    #pragma unroll
    for (int qt = 0; qt < 2; ++qt) {
      acc1[qt] = zero;
      #pragma unroll
      for (int nt = 0; nt < 8; ++nt) acc[qt][nt] = zero;
    }

    // prologue: stage first k-tile into buf0
    if (kcount > 0) {
      #pragma unroll
      for (int ji = 0; ji < 8; ++ji) {
        int j = w * 8 + ji;
        const ushort* src = kbb + (size_t)(kbase * 32 + j) * DDIM + ((lane ^ ji) << 3);
        __builtin_amdgcn_global_load_lds((const AS1 void*)src,
            (AS3 void*)(ldsK + j * 1024), 16, 0, 0);
      }
    }
    asm volatile("s_waitcnt vmcnt(0) lgkmcnt(0)" ::: "memory");
    __builtin_amdgcn_s_barrier();

    const int i_row = q0 + qs * 16 + g * 4;

    for (int i = 0; i < H; ++i) {
      const bool act = (i < kcount);
      const int kt = kbase + i;
      const int pp = i & 1;
      char* kbuf  = ldsK + (i & 1) * 32768;
      char* kbufn = ldsK + ((i & 1) ^ 1) * 32768;

      // V fragments direct from global (L2/L3-resident), full-iter slack
      bf16x8 vb[8];
      if (act) {
        #pragma unroll
        for (int nt = 0; nt < 8; ++nt)
          vb[nt] = *(const bf16x8*)(vtb + (size_t)(dw0 + nt * 16 + m16) * SDIM + kt * 32 + g * 8);
      }
      // dbuf: stage next k-tile now; waited at iteration end (full slack)
      if (i + 1 < kcount) {
        #pragma unroll
        for (int ji = 0; ji < 8; ++ji) {
          int j = w * 8 + ji;
          const ushort* src = kbb + (size_t)((kt + 1) * 32 + j) * DDIM + ((lane ^ ji) << 3);
          __builtin_amdgcn_global_load_lds((const AS1 void*)src,
              (AS3 void*)(kbufn + j * 1024), 16, 0, 0);
        }
      }

      float sc[4];
      if (act) {
        // ---- QK^T ----
        f32x4 s0 = zero, s1 = zero;
        const char* kptr = kbuf + (ks * 16 + m16) * 1024;
        const unsigned ksw = (unsigned)((m16 & 7) << 4);
        __builtin_amdgcn_s_setprio(1);
        #pragma unroll
        for (int ds = 0; ds < 16; ds += 2) {
          bf16x8 k0f = *(const bf16x8*)(kptr + (((unsigned)(ds * 64 + g * 16)) ^ ksw));
          s0 = __builtin_amdgcn_mfma_f32_16x16x32_bf16(qf[ds], k0f, s0, 0, 0, 0);
          bf16x8 k1f = *(const bf16x8*)(kptr + (((unsigned)((ds + 1) * 64 + g * 16)) ^ ksw));
          s1 = __builtin_amdgcn_mfma_f32_16x16x32_bf16(qf[ds + 1], k1f, s1, 0, 0, 0);
        }
        __builtin_amdgcn_s_setprio(0);

        const int j_col = kt * 32 + ks * 16 + m16;
        const bool diag = (kt == t);
        #pragma unroll
        for (int jj = 0; jj < 4; ++jj) {
          float d = (float)(i_row + jj - j_col);
          float bias = __builtin_amdgcn_rcpf(fmaf(0.2f * d, d, 1.0f));
          float s = s0[jj] + s1[jj] + bias;
          if (diag && (j_col > i_row + jj)) s = -1e30f;
          sc[jj] = s;
        }
        #pragma unroll
        for (int jj = 0; jj < 4; ++jj) {
          float v = sc[jj];
          v = fmaxf(v, __shfl_xor(v, 1));
          v = fmaxf(v, __shfl_xor(v, 2));
          v = fmaxf(v, __shfl_xor(v, 4));
          v = fmaxf(v, __shfl_xor(v, 8));
          if (m16 == 0) pmx[ks * 32 + qs * 16 + g * 4 + jj] = v;
        }
      }
      asm volatile("s_waitcnt lgkmcnt(0)" ::: "memory");
      __builtin_amdgcn_s_barrier();                    // [B] pmax visible

      if (act) {
        const int row = lane & 31;
        float mo = mrow[pp * 32 + row];
        float tm = fmaxf(pmx[row], pmx[32 + row]);
        bool upd = tm > mo + 8.0f;                     // defer-max THR=8
        float mn = upd ? tm : mo;
        float rr = upd ? __expf(mo - tm) : 1.0f;
        if (w == 0 && lane < 32) mrow[(pp ^ 1) * 32 + row] = mn;

        #pragma unroll
        for (int jj = 0; jj < 4; ++jj) {
          float mq = __shfl(mn, qs * 16 + g * 4 + jj);
          float p = __expf(sc[jj] - mq);
          psh[(qs * 16 + g * 4 + jj) * 40 + ks * 16 + m16] = f2bf(p);
        }
        if (!__all(rr == 1.0f)) {
          #pragma unroll
          for (int qt = 0; qt < 2; ++qt)
            #pragma unroll
            for (int jj = 0; jj < 4; ++jj) {
              float r2 = __shfl(rr, qt * 16 + g * 4 + jj);
              #pragma unroll
              for (int nt = 0; nt < 8; ++nt) acc[qt][nt][jj] *= r2;
              acc1[qt][jj] *= r2;
            }
        }
      }
      asm volatile("s_waitcnt lgkmcnt(0)" ::: "memory");
      __builtin_amdgcn_s_barrier();                    // [C] Psh visible

      if (act) {
        bf16x8 pa[2];
        #pragma unroll
        for (int qt = 0; qt < 2; ++qt)
          pa[qt] = *(const bf16x8*)((const char*)psh + (qt * 16 + m16) * 80 + g * 16);
        __builtin_amdgcn_s_setprio(1);
        #pragma unroll
        for (int nt = 0; nt < 8; ++nt) {
          acc[0][nt] = __builtin_amdgcn_mfma_f32_16x16x32_bf16(pa[0], vb[nt], acc[0][nt], 0, 0, 0);
          acc[1][nt] = __builtin_amdgcn_mfma_f32_16x16x32_bf16(pa[1], vb[nt], acc[1][nt], 0, 0, 0);
        }
        acc1[0] = __builtin_amdgcn_mfma_f32_16x16x32_bf16(pa[0], ones, acc1[0], 0, 0, 0);
        acc1[1] = __builtin_amdgcn_mfma_f32_16x16x32_bf16(pa[1], ones, acc1[1], 0, 0, 0);
        __builtin_amdgcn_s_setprio(0);
      }
      // [A] next K buf landed (full-iteration slack); Psh consumed
      asm volatile("s_waitcnt vmcnt(0) lgkmcnt(0)" ::: "memory");
      __builtin_amdgcn_s_barrier();
    }

    // ---- merge group1 partials into group0, write out ----
    if (grp == 1) {
      f32x4* sa = (f32x4*)(lds + w * 18432);
      float* sl = (float*)(lds + w * 18432 + 16384);
      #pragma unroll
      for (int qt = 0; qt < 2; ++qt) {
        #pragma unroll
        for (int nt = 0; nt < 8; ++nt) sa[lane * 16 + qt * 8 + nt] = acc[qt][nt];
        #pragma unroll
        for (int jj = 0; jj < 4; ++jj) sl[lane * 8 + qt * 4 + jj] = acc1[qt][jj];
      }
    }
    asm volatile("s_waitcnt lgkmcnt(0)" ::: "memory");
    __builtin_amdgcn_s_barrier();
    if (grp == 0) {
      const int cnt1 = t + 1 - H;
      const float* mBb = (const float*)(lds + 136192 + 256) + (cnt1 & 1) * 32;
      const float* mAb = mrow + (H & 1) * 32;
      const f32x4* sa = (const f32x4*)(lds + w * 18432);
      const float* sl = (const float*)(lds + w * 18432 + 16384);
      #pragma unroll
      for (int qt = 0; qt < 2; ++qt) {
        #pragma unroll
        for (int jj = 0; jj < 4; ++jj) {
          const int row = qt * 16 + g * 4 + jj;
          float mA = mAb[row], mB = mBb[row];
          float ms = fmaxf(mA, mB);
          float eA = __expf(mA - ms), eB = __expf(mB - ms);
          float lB = sl[lane * 8 + qt * 4 + jj];
          float li = 1.0f / (acc1[qt][jj] * eA + lB * eB);
          float* orow = out + ((size_t)b * SDIM + q0 + row) * DDIM + dw0 + m16;
          #pragma unroll
          for (int nt = 0; nt < 8; ++nt) {
            float ob = sa[lane * 16 + qt * 8 + nt][jj];
            orow[nt * 16] = (acc[qt][nt][jj] * eA + ob * eB) * li;
          }
        }
      }
    }
    asm volatile("s_waitcnt vmcnt(0) lgkmcnt(0)" ::: "memory");
    __builtin_amdgcn_s_barrier();    // scratch/K region reusable by next tile
  }
}

extern "C" void kernel_launch(void* const* d_in, const int* in_sizes, int n_in,
                              void* d_out, int out_size, void* d_ws, size_t ws_size,
                              hipStream_t stream) {
  const float* Q = (const float*)d_in[0];
  const float* K = (const float*)d_in[1];
  const float* V = (const float*)d_in[2];
  float* out = (float*)d_out;
  ushort* Kb = (ushort*)d_ws;                                  // 16.78 MB
  ushort* Vt = Kb + (size_t)NB * SDIM * DDIM;                  // 16.78 MB
  convert_k<<<2048, 256, 0, stream>>>(K, Kb);
  transpose_v<<<2048, 256, 0, stream>>>(V, Vt);
  attn<<<256, 512, 0, stream>>>(Q, Kb, Vt, out);
}